// Round 9
// baseline (161.049 us; speedup 1.0000x reference)
//
#include <hip/hip_runtime.h>
#include <hip/hip_bf16.h>
#include <math.h>

// NT-Xent loss, N=4096, D=256, symmetric-GEMM version.
// loss = (1/2N) * sum_i [ 2 + log( sum_{j != i} exp(2*dot_ij - 2) ) - 2*dot(zn_i, zn_pair(i)) ]
//
// ROUND-9 MODEL: rounds 0-8 showed every {LDS-stage -> barrier -> compute ->
// barrier} variant lands at ~44 us (8 block-wide rendezvous per tile, load
// latency exposed to all waves, ~1.3 blocks/CU co-resident); pipelining within
// the skeleton is null (r1/r7) or racy (r5/r6); fewer blocks regress (r4/r8).
// Fix: DELETE the skeleton. zn is 4 MB (< one XCD L2), so MFMA fragments are
// read DIRECTLY from global/L2 -- per-lane 16B contiguous, 64B lines fully
// consumed. K-loop = 64 loads + 128 MFMAs per wave, ZERO barriers; waves stay
// independent until the epilogue. L2 traffic doubles (bandwidth cost) but the
// latency x barrier product disappears and occupancy is VGPR-capped only
// (launch_bounds(256,4) -> <=128 VGPR -> 4 blocks/CU).
// K1: normalize rows -> bf16 zn in ws; zero rowtotal[8192], ticket and out.
// K2: 2080 upper-tri 128x128 tiles, 4 waves each, direct-global MFMA; XCD-
//     bijective swizzle (2080 = 8*260) keeps same-jb panels XCD-local (T1).
//     Epilogue + rowtotal flush verbatim round 0; ticket finalize verbatim
//     round 4 (harness-verified 3x).

using short8  = __attribute__((ext_vector_type(8))) short;
using floatx4 = __attribute__((ext_vector_type(4))) float;

constexpr int TWO_N = 8192;
constexpr int DIM   = 256;
constexpr int NB    = 64;                 // 8192/128 tile blocks per side
constexpr int NTRI  = NB * (NB + 1) / 2;  // 2080
constexpr float INV2N = 1.0f / 8192.0f;

__device__ static inline unsigned short f2bf(float f) {
  unsigned u = __float_as_uint(f);
  return (unsigned short)((u + 0x7fffu + ((u >> 16) & 1u)) >> 16);  // RNE
}

// ---------------- K1: normalize + cast to bf16, zero accumulators ----------------
__global__ __launch_bounds__(256) void k_normalize(
    const float* __restrict__ zi, const float* __restrict__ zj,
    __hip_bfloat16* __restrict__ zn, float* __restrict__ rowtotal,
    float* __restrict__ out, unsigned* __restrict__ ticket)
{
  if (blockIdx.x == 0 && threadIdx.x == 0) { out[0] = 0.0f; ticket[0] = 0u; }
  if (blockIdx.x < 32) rowtotal[blockIdx.x * 256 + threadIdx.x] = 0.0f;

  const int lane = threadIdx.x & 63;
  const int wave = threadIdx.x >> 6;
  const int row  = blockIdx.x * 4 + wave;
  const float* src = (row < 4096) ? (zi + (size_t)row * DIM)
                                  : (zj + (size_t)(row - 4096) * DIM);
  float4 v = reinterpret_cast<const float4*>(src)[lane];
  float ss = v.x * v.x + v.y * v.y + v.z * v.z + v.w * v.w;
#pragma unroll
  for (int m = 32; m >= 1; m >>= 1) ss += __shfl_xor(ss, m, 64);
  float inv = 1.0f / fmaxf(sqrtf(ss), 1e-8f);
  ushort4 o;
  o.x = f2bf(v.x * inv); o.y = f2bf(v.y * inv);
  o.z = f2bf(v.z * inv); o.w = f2bf(v.w * inv);
  reinterpret_cast<ushort4*>(zn + (size_t)row * DIM)[lane] = o;
}

// ---------------- K2: direct-global MFMA triangular GEMM + fused epilogue ----------------
// block 256 = 4 waves in 2x2; wave owns 64x64 (4x4 of 16x16x32 accumulators).
// A fragment (mt,kk,ks): 16B at Z[(i0+wm*64+mt*16+c16)*256 + kk*64+ks*32+q*8];
// B likewise with j0/wn/nt. No LDS in the K-loop, no barriers until epilogue.
__global__ __launch_bounds__(256, 4) void k_simexp(
    const __hip_bfloat16* __restrict__ Z, float* __restrict__ rowtotal,
    float* __restrict__ out, unsigned* __restrict__ ticket)
{
  __shared__ float rowsum[128];
  __shared__ float colsum[128];
  __shared__ float finsum[4];
  __shared__ int lastflag;

  const int tid  = threadIdx.x;
  const int lane = tid & 63;
  const int wave = tid >> 6;
  const int wm   = wave >> 1;   // output row half
  const int wn   = wave & 1;    // output col half
  const int q    = lane >> 4;   // 0..3
  const int c16  = lane & 15;

  // XCD-bijective chunked swizzle: 2080 = 8 * 260. XCD x walks a contiguous
  // u-range -> same-jb panel reuse stays in one XCD's L2. (T1)
  const int bid = blockIdx.x;
  const int u   = (bid & 7) * (NTRI / 8) + (bid >> 3);

  // triangular decode: u -> (ib <= jb)
  int jb = (int)((sqrtf(8.0f * (float)u + 1.0f) - 1.0f) * 0.5f);
  while ((jb + 1) * (jb + 2) / 2 <= u) ++jb;
  while (jb * (jb + 1) / 2 > u) --jb;
  const int ib = u - jb * (jb + 1) / 2;

  const bool diagblk = (ib == jb);
  const bool pairblk = (jb == ib + 32);
  const int i0 = ib * 128;
  const int j0 = jb * 128;

  if (tid < 128) { rowsum[tid] = 0.0f; colsum[tid] = 0.0f; }

  // per-lane fragment row bases (mt/nt advance by 16 rows = 8 KB)
  const __hip_bfloat16* arow = Z + (size_t)(i0 + wm * 64 + c16) * DIM;
  const __hip_bfloat16* brow = Z + (size_t)(j0 + wn * 64 + c16) * DIM;

  floatx4 acc[4][4] = {};

#pragma unroll
  for (int kk = 0; kk < 4; ++kk) {
#pragma unroll
    for (int ks = 0; ks < 2; ++ks) {
      const int kofs = kk * 64 + ks * 32 + q * 8;
      short8 a[4], b[4];
#pragma unroll
      for (int mt = 0; mt < 4; ++mt)
        a[mt] = *reinterpret_cast<const short8*>(arow + mt * 16 * DIM + kofs);
#pragma unroll
      for (int nt = 0; nt < 4; ++nt)
        b[nt] = *reinterpret_cast<const short8*>(brow + nt * 16 * DIM + kofs);
#pragma unroll
      for (int mt = 0; mt < 4; ++mt)
#pragma unroll
        for (int nt = 0; nt < 4; ++nt)
          acc[mt][nt] = __builtin_amdgcn_mfma_f32_16x16x32_bf16(
              a[mt], b[nt], acc[mt][nt], 0, 0, 0);
    }
  }

  __syncthreads();   // rowsum/colsum init visible before epilogue LDS atomics

  // ---- epilogue (verbatim round 0) ----
  // C/D layout: col = lane&15 (within nt-tile), row = q*4 + reg (within mt-tile).
  float colacc[4] = {0.f, 0.f, 0.f, 0.f};
  float pc = 0.f;
  const bool diagwave = (wm == wn);

#pragma unroll
  for (int mt = 0; mt < 4; ++mt) {
#pragma unroll
    for (int reg = 0; reg < 4; ++reg) {
      const bool onquad = (c16 == q * 4 + reg);  // lane holds a subtile-diag elem
      float s = 0.0f;
#pragma unroll
      for (int nt = 0; nt < 4; ++nt) {
        float e = __expf(2.0f * acc[mt][nt][reg] - 2.0f);
        bool skip = diagblk && diagwave && (nt == mt) && onquad;  // true self-sim
        s += skip ? 0.0f : e;
        colacc[nt] += e;
      }
      if (pairblk && diagwave && onquad) pc += acc[mt][mt][reg];  // pair dot
      s += __shfl_xor(s, 1, 64);
      s += __shfl_xor(s, 2, 64);
      s += __shfl_xor(s, 4, 64);
      s += __shfl_xor(s, 8, 64);
      if (c16 == 0)
        atomicAdd(&rowsum[wm * 64 + mt * 16 + q * 4 + reg], s);
    }
  }

  if (!diagblk) {
#pragma unroll
    for (int nt = 0; nt < 4; ++nt) {
      float cs = colacc[nt];
      cs += __shfl_xor(cs, 16, 64);
      cs += __shfl_xor(cs, 32, 64);
      if (lane < 16) atomicAdd(&colsum[wn * 64 + nt * 16 + lane], cs);
    }
  }

  if (pairblk && diagwave) {
#pragma unroll
    for (int m = 32; m >= 1; m >>= 1) pc += __shfl_xor(pc, m, 64);
    // each pair diag elem covers rows i and i+4096: loss += -2*(2*dot) per pair
    if (lane == 0) atomicAdd(out, -4.0f * pc * INV2N);
  }

  __syncthreads();
  if (tid < 128) {
    atomicAdd(&rowtotal[i0 + tid], rowsum[tid]);
    if (!diagblk) atomicAdd(&rowtotal[j0 + tid], colsum[tid]);
  }

  // ---- fence-free ticket finalize (verbatim round 4, harness-verified) ----
  // __syncthreads drains vmcnt(0): this block's device-scope rowtotal atomics
  // reached the coherence point before the ticket bump.
  __syncthreads();
  if (tid == 0) lastflag = (atomicAdd(ticket, 1u) == (unsigned)(NTRI - 1)) ? 1 : 0;
  __syncthreads();
  if (lastflag) {
    __threadfence();      // acquire side; ONE block only (cheap)
    float v = 0.0f;
#pragma unroll 4
    for (int r = tid; r < TWO_N; r += 256) {
      float tv = __hip_atomic_load(&rowtotal[r], __ATOMIC_RELAXED,
                                   __HIP_MEMORY_SCOPE_AGENT);
      v += 2.0f + __logf(tv);
    }
#pragma unroll
    for (int m = 32; m >= 1; m >>= 1) v += __shfl_xor(v, m, 64);
    if (lane == 0) finsum[wave] = v;
    __syncthreads();
    if (tid == 0)
      atomicAdd(out, (finsum[0] + finsum[1] + finsum[2] + finsum[3]) * INV2N);
  }
}

// ---------------- launch ----------------
extern "C" void kernel_launch(void* const* d_in, const int* in_sizes, int n_in,
                              void* d_out, int out_size, void* d_ws, size_t ws_size,
                              hipStream_t stream) {
  const float* zi = (const float*)d_in[0];
  const float* zj = (const float*)d_in[1];
  float* out = (float*)d_out;

  __hip_bfloat16* zn = (__hip_bfloat16*)d_ws;                        // 8192*256*2 = 4 MB
  float* rowtotal = (float*)((char*)d_ws + (size_t)TWO_N * DIM * 2); // 8192*4 = 32 KB
  unsigned* ticket = (unsigned*)((char*)d_ws + (size_t)TWO_N * DIM * 2 + (size_t)TWO_N * 4);

  k_normalize<<<dim3(TWO_N / 4), dim3(256), 0, stream>>>(zi, zj, zn, rowtotal, out, ticket);
  k_simexp<<<dim3(NTRI), dim3(256), 0, stream>>>(zn, rowtotal, out, ticket);
}

// Round 10
// 116.396 us; speedup vs baseline: 1.3836x; 1.3836x over previous
//
#include <hip/hip_runtime.h>
#include <hip/hip_bf16.h>
#include <math.h>

// NT-Xent loss, N=4096, D=256, symmetric-GEMM version.
// loss = (1/2N) * sum_i [ 2 + log( sum_{j != i} exp(2*dot_ij - 2) ) - 2*dot(zn_i, zn_pair(i)) ]
//
// ROUND-10 MODEL: r0/r3/r7 (LDS+barrier skeleton) pin at ~44 us (barrier-coupled,
// K=256 too short for steady state); r9 (direct-global) hit 102 us because MFMA
// fragment loads were 16-segment gathers (lane addr = c16*512B + q*16B).
// Fix: FRAGMENT-MAJOR zn layout, chosen so operand loads are contiguous:
//   znf[G*4096 + g8*128 + c*8 + e] = zn[G*16+c][g8*8+e]   (G=row/16, g8=k/8)
// A-fragment load at lane (q,c16): base + q*256B + c16*16B = ONE 1KB segment.
// K2 = r9's verified kernel (absmax 0.0) with only address arithmetic changed,
// no LDS staging, no K-loop barriers, no VGPR cap (r9's (256,4) cap killed
// prefetch depth). Compiler pipelines the 64 loads freely (no aliasing).
// K1: normalize rows -> znf (fragment-major write); zero rowtotal/ticket/out.
// K2: 2080 upper-tri 128x128 tiles, XCD-bijective swizzle, fused exp epilogue,
//     fence-free ticket finalize (verified r1/2/4/8/9).

using short8  = __attribute__((ext_vector_type(8))) short;
using floatx4 = __attribute__((ext_vector_type(4))) float;

constexpr int TWO_N = 8192;
constexpr int DIM   = 256;
constexpr int NB    = 64;                 // 8192/128 tile blocks per side
constexpr int NTRI  = NB * (NB + 1) / 2;  // 2080
constexpr float INV2N = 1.0f / 8192.0f;

__device__ static inline unsigned short f2bf(float f) {
  unsigned u = __float_as_uint(f);
  return (unsigned short)((u + 0x7fffu + ((u >> 16) & 1u)) >> 16);  // RNE
}

// ---------------- K1: normalize + cast to bf16 (fragment-major write) ----------------
__global__ __launch_bounds__(256) void k_normalize(
    const float* __restrict__ zi, const float* __restrict__ zj,
    __hip_bfloat16* __restrict__ znf, float* __restrict__ rowtotal,
    float* __restrict__ out, unsigned* __restrict__ ticket)
{
  if (blockIdx.x == 0 && threadIdx.x == 0) { out[0] = 0.0f; ticket[0] = 0u; }
  if (blockIdx.x < 32) rowtotal[blockIdx.x * 256 + threadIdx.x] = 0.0f;

  const int lane = threadIdx.x & 63;
  const int wave = threadIdx.x >> 6;
  const int row  = blockIdx.x * 4 + wave;
  const float* src = (row < 4096) ? (zi + (size_t)row * DIM)
                                  : (zj + (size_t)(row - 4096) * DIM);
  float4 v = reinterpret_cast<const float4*>(src)[lane];
  float ss = v.x * v.x + v.y * v.y + v.z * v.z + v.w * v.w;
#pragma unroll
  for (int m = 32; m >= 1; m >>= 1) ss += __shfl_xor(ss, m, 64);
  float inv = 1.0f / fmaxf(sqrtf(ss), 1e-8f);
  ushort4 o;
  o.x = f2bf(v.x * inv); o.y = f2bf(v.y * inv);
  o.z = f2bf(v.z * inv); o.w = f2bf(v.w * inv);
  // lane holds elems k = 4*lane .. 4*lane+3 of this row.
  // fragment-major dst: G = row/16, c = row%16, g8 = k/8 = lane>>1,
  // within-octet = (lane&1)*4.  dst elem = G*4096 + g8*128 + c*8 + (lane&1)*4.
  const int G = row >> 4, c = row & 15;
  *reinterpret_cast<ushort4*>(
      znf + (size_t)G * 4096 + (lane >> 1) * 128 + c * 8 + (lane & 1) * 4) = o;
}

// ---------------- K2: direct-global MFMA (fragment-major) + fused epilogue ----------------
// block 256 = 4 waves in 2x2; wave owns 64x64 (4x4 of 16x16x32 accumulators).
// a[mt] for lane (q,c16): znf elems (Ga+mt)*4096 + (8kk+4ks)*128 + lane*8
// == A[row = (Ga+mt)*16 + c16][k = kk*64+ks*32+q*8 .. +7]  (r9-verified mapping).
// Per-wave load = 64 lanes x 16B contiguous 1KB. No LDS staging, no K barriers.
__global__ __launch_bounds__(256) void k_simexp(
    const __hip_bfloat16* __restrict__ znf, float* __restrict__ rowtotal,
    float* __restrict__ out, unsigned* __restrict__ ticket)
{
  __shared__ float rowsum[128];
  __shared__ float colsum[128];
  __shared__ float finsum[4];
  __shared__ int lastflag;

  const int tid  = threadIdx.x;
  const int lane = tid & 63;
  const int wave = tid >> 6;
  const int wm   = wave >> 1;   // output row half
  const int wn   = wave & 1;    // output col half
  const int q    = lane >> 4;   // 0..3
  const int c16  = lane & 15;

  // XCD-bijective chunked swizzle: 2080 = 8 * 260 (T1)
  const int bid = blockIdx.x;
  const int u   = (bid & 7) * (NTRI / 8) + (bid >> 3);

  // triangular decode: u -> (ib <= jb)
  int jb = (int)((sqrtf(8.0f * (float)u + 1.0f) - 1.0f) * 0.5f);
  while ((jb + 1) * (jb + 2) / 2 <= u) ++jb;
  while (jb * (jb + 1) / 2 > u) --jb;
  const int ib = u - jb * (jb + 1) / 2;

  const bool diagblk = (ib == jb);
  const bool pairblk = (jb == ib + 32);
  const int i0 = ib * 128;
  const int j0 = jb * 128;

  if (tid < 128) { rowsum[tid] = 0.0f; colsum[tid] = 0.0f; }

  // panel bases: 16-row group index Ga = ib*8 + wm*4 (+mt), Gb = jb*8 + wn*4 (+nt)
  const __hip_bfloat16* apan = znf + (size_t)(ib * 8 + wm * 4) * 4096 + lane * 8;
  const __hip_bfloat16* bpan = znf + (size_t)(jb * 8 + wn * 4) * 4096 + lane * 8;

  floatx4 acc[4][4] = {};

#pragma unroll
  for (int kk = 0; kk < 4; ++kk) {
#pragma unroll
    for (int ks = 0; ks < 2; ++ks) {
      const int koff = kk * 1024 + ks * 512;   // (8*kk+4*ks)*128 elems
      short8 a[4], b[4];
#pragma unroll
      for (int mt = 0; mt < 4; ++mt)
        a[mt] = *reinterpret_cast<const short8*>(apan + mt * 4096 + koff);
#pragma unroll
      for (int nt = 0; nt < 4; ++nt)
        b[nt] = *reinterpret_cast<const short8*>(bpan + nt * 4096 + koff);
#pragma unroll
      for (int mt = 0; mt < 4; ++mt)
#pragma unroll
        for (int nt = 0; nt < 4; ++nt)
          acc[mt][nt] = __builtin_amdgcn_mfma_f32_16x16x32_bf16(
              a[mt], b[nt], acc[mt][nt], 0, 0, 0);
    }
  }

  __syncthreads();   // rowsum/colsum init visible before epilogue LDS atomics

  // ---- epilogue (verbatim r0/r9) ----
  // C/D layout: col = lane&15 (within nt-tile), row = q*4 + reg (within mt-tile).
  float colacc[4] = {0.f, 0.f, 0.f, 0.f};
  float pc = 0.f;
  const bool diagwave = (wm == wn);

#pragma unroll
  for (int mt = 0; mt < 4; ++mt) {
#pragma unroll
    for (int reg = 0; reg < 4; ++reg) {
      const bool onquad = (c16 == q * 4 + reg);  // lane holds a subtile-diag elem
      float s = 0.0f;
#pragma unroll
      for (int nt = 0; nt < 4; ++nt) {
        float e = __expf(2.0f * acc[mt][nt][reg] - 2.0f);
        bool skip = diagblk && diagwave && (nt == mt) && onquad;  // true self-sim
        s += skip ? 0.0f : e;
        colacc[nt] += e;
      }
      if (pairblk && diagwave && onquad) pc += acc[mt][mt][reg];  // pair dot
      s += __shfl_xor(s, 1, 64);
      s += __shfl_xor(s, 2, 64);
      s += __shfl_xor(s, 4, 64);
      s += __shfl_xor(s, 8, 64);
      if (c16 == 0)
        atomicAdd(&rowsum[wm * 64 + mt * 16 + q * 4 + reg], s);
    }
  }

  if (!diagblk) {
#pragma unroll
    for (int nt = 0; nt < 4; ++nt) {
      float cs = colacc[nt];
      cs += __shfl_xor(cs, 16, 64);
      cs += __shfl_xor(cs, 32, 64);
      if (lane < 16) atomicAdd(&colsum[wn * 64 + nt * 16 + lane], cs);
    }
  }

  if (pairblk && diagwave) {
#pragma unroll
    for (int m = 32; m >= 1; m >>= 1) pc += __shfl_xor(pc, m, 64);
    // each pair diag elem covers rows i and i+4096: loss += -2*(2*dot) per pair
    if (lane == 0) atomicAdd(out, -4.0f * pc * INV2N);
  }

  __syncthreads();
  if (tid < 128) {
    atomicAdd(&rowtotal[i0 + tid], rowsum[tid]);
    if (!diagblk) atomicAdd(&rowtotal[j0 + tid], colsum[tid]);
  }

  // ---- fence-free ticket finalize (verified r1/2/4/8/9) ----
  __syncthreads();
  if (tid == 0) lastflag = (atomicAdd(ticket, 1u) == (unsigned)(NTRI - 1)) ? 1 : 0;
  __syncthreads();
  if (lastflag) {
    __threadfence();      // acquire side; ONE block only (cheap)
    float v = 0.0f;
#pragma unroll 4
    for (int r = tid; r < TWO_N; r += 256) {
      float tv = __hip_atomic_load(&rowtotal[r], __ATOMIC_RELAXED,
                                   __HIP_MEMORY_SCOPE_AGENT);
      v += 2.0f + __logf(tv);
    }
#pragma unroll
    for (int m = 32; m >= 1; m >>= 1) v += __shfl_xor(v, m, 64);
    if (lane == 0) finsum[wave] = v;
    __syncthreads();
    if (tid == 0)
      atomicAdd(out, (finsum[0] + finsum[1] + finsum[2] + finsum[3]) * INV2N);
  }
}

// ---------------- launch ----------------
extern "C" void kernel_launch(void* const* d_in, const int* in_sizes, int n_in,
                              void* d_out, int out_size, void* d_ws, size_t ws_size,
                              hipStream_t stream) {
  const float* zi = (const float*)d_in[0];
  const float* zj = (const float*)d_in[1];
  float* out = (float*)d_out;

  __hip_bfloat16* znf = (__hip_bfloat16*)d_ws;                       // 8192*256*2 = 4 MB
  float* rowtotal = (float*)((char*)d_ws + (size_t)TWO_N * DIM * 2); // 8192*4 = 32 KB
  unsigned* ticket = (unsigned*)((char*)d_ws + (size_t)TWO_N * DIM * 2 + (size_t)TWO_N * 4);

  k_normalize<<<dim3(TWO_N / 4), dim3(256), 0, stream>>>(zi, zj, znf, rowtotal, out, ticket);
  k_simexp<<<dim3(NTRI), dim3(256), 0, stream>>>(znf, rowtotal, out, ticket);
}

// Round 11
// 112.338 us; speedup vs baseline: 1.4336x; 1.0361x over previous
//
#include <hip/hip_runtime.h>
#include <hip/hip_bf16.h>
#include <math.h>

// NT-Xent loss, N=4096, D=256, symmetric-GEMM version.
// loss = (1/2N) * sum_i [ 2 + log( sum_{j != i} exp(2*dot_ij - 2) ) - 2*dot(zn_i, zn_pair(i)) ]
//
// ROUND-11: r0/r3/r7 skeleton is invariant at ~44 us across geometry/staging;
// the only untested axis is drains/barriers per block. BK=128 halves them:
// 2 stage-drains (16-deep DMA issue each) + 3 barriers per tile, LDS 64 KB ->
// still 2 blocks/CU co-resident (r4 showed 1 block/CU serializes). Sub-tile
// addressing/swizzle byte-identical to r0 (outer [ksub] stride only).
// Plus proven freebies: XCD-bijective swizzle (r10: FETCH 16.5->12 MB) and
// fence-free ticket finalize (passed r1/2/4/9/10).
// K1: normalize rows -> bf16 zn (row-major); zero rowtotal/ticket/out.
// K2: 2080 upper-tri 128x128 tiles, 4 waves 2x2, BK=128 x 2 K-halves,
//     fused exp epilogue -> rowtotal atomics, pair/diag handling, ticket.

using short8  = __attribute__((ext_vector_type(8))) short;
using floatx4 = __attribute__((ext_vector_type(4))) float;

constexpr int TWO_N = 8192;
constexpr int DIM   = 256;
constexpr int NB    = 64;                 // 8192/128 tile blocks per side
constexpr int NTRI  = NB * (NB + 1) / 2;  // 2080
constexpr float INV2N = 1.0f / 8192.0f;

__device__ static inline unsigned short f2bf(float f) {
  unsigned u = __float_as_uint(f);
  return (unsigned short)((u + 0x7fffu + ((u >> 16) & 1u)) >> 16);  // RNE
}

__device__ static inline void async_copy16(const __hip_bfloat16* g, __hip_bfloat16* l) {
  __builtin_amdgcn_global_load_lds(
      (const __attribute__((address_space(1))) void*)(const void*)g,
      (__attribute__((address_space(3))) void*)(void*)l, 16, 0, 0);
}

// ---------------- K1: normalize + cast to bf16, zero accumulators ----------------
__global__ __launch_bounds__(256) void k_normalize(
    const float* __restrict__ zi, const float* __restrict__ zj,
    __hip_bfloat16* __restrict__ zn, float* __restrict__ rowtotal,
    float* __restrict__ out, unsigned* __restrict__ ticket)
{
  if (blockIdx.x == 0 && threadIdx.x == 0) { out[0] = 0.0f; ticket[0] = 0u; }
  if (blockIdx.x < 32) rowtotal[blockIdx.x * 256 + threadIdx.x] = 0.0f;

  const int lane = threadIdx.x & 63;
  const int wave = threadIdx.x >> 6;
  const int row  = blockIdx.x * 4 + wave;
  const float* src = (row < 4096) ? (zi + (size_t)row * DIM)
                                  : (zj + (size_t)(row - 4096) * DIM);
  float4 v = reinterpret_cast<const float4*>(src)[lane];
  float ss = v.x * v.x + v.y * v.y + v.z * v.z + v.w * v.w;
#pragma unroll
  for (int m = 32; m >= 1; m >>= 1) ss += __shfl_xor(ss, m, 64);
  float inv = 1.0f / fmaxf(sqrtf(ss), 1e-8f);
  ushort4 o;
  o.x = f2bf(v.x * inv); o.y = f2bf(v.y * inv);
  o.z = f2bf(v.z * inv); o.w = f2bf(v.w * inv);
  reinterpret_cast<ushort4*>(zn + (size_t)row * DIM)[lane] = o;
}

// ---------------- K2: BK=128 triangular GEMM + fused exp epilogue + ticket ----------------
// block 256 = 4 waves in 2x2; wave owns 64x64 (4x4 of 16x16x32 accumulators).
// LDS: As/Bs = 2 sub-tiles of [128][64] bf16 each (one K-half), r0 swizzle
// within each sub-tile: phys 16B slot = logical ^ (row&7).
__global__ __launch_bounds__(256) void k_simexp(
    const __hip_bfloat16* __restrict__ Z, float* __restrict__ rowtotal,
    float* __restrict__ out, unsigned* __restrict__ ticket)
{
  __shared__ __align__(16) __hip_bfloat16 As[2][128 * 64];  // [ksub][row*64+slot]
  __shared__ __align__(16) __hip_bfloat16 Bs[2][128 * 64];
  __shared__ float rowsum[128];
  __shared__ float colsum[128];
  __shared__ float finsum[4];
  __shared__ int lastflag;

  const int tid  = threadIdx.x;
  const int lane = tid & 63;
  const int wave = tid >> 6;
  const int wm   = wave >> 1;   // output row half
  const int wn   = wave & 1;    // output col half

  // XCD-bijective chunked swizzle: 2080 = 8 * 260 (T1, verified r9/r10)
  const int bid = blockIdx.x;
  const int u   = (bid & 7) * (NTRI / 8) + (bid >> 3);

  // triangular decode: u -> (ib <= jb)
  int jb = (int)((sqrtf(8.0f * (float)u + 1.0f) - 1.0f) * 0.5f);
  while ((jb + 1) * (jb + 2) / 2 <= u) ++jb;
  while (jb * (jb + 1) / 2 > u) --jb;
  const int ib = u - jb * (jb + 1) / 2;

  const bool diagblk = (ib == jb);
  const bool pairblk = (jb == ib + 32);
  const int i0 = ib * 128;
  const int j0 = jb * 128;

  if (tid < 128) { rowsum[tid] = 0.0f; colsum[tid] = 0.0f; }

  floatx4 acc[4][4] = {};

  const int lane7 = lane & 7;
  const int sub   = lane >> 3;               // 0..7 subrow within 8-row segment
  const int gkoff = ((lane7 ^ sub) << 3);    // swizzled logical 16B slot to fetch
  const int q     = lane >> 4;               // 0..3
  const int c16   = lane & 15;

  // staging bases: waves 0,1 -> As (rows 0..63 / 64..127), waves 2,3 -> Bs
  const __hip_bfloat16* gbase =
      Z + (size_t)((wave < 2 ? i0 : j0) + (wave & 1) * 64) * DIM;
  const int lboff = (wave & 1) * 64 * 64;

  // ---- K loop: 2 halves of BK=128, each = 2 swizzled [128][64] sub-tiles ----
#pragma unroll
  for (int h = 0; h < 2; ++h) {
    // stage both sub-tiles of this half: 16 DMA per wave, issued back-to-back
#pragma unroll
    for (int ksub = 0; ksub < 2; ++ksub) {
      const int k0 = h * 128 + ksub * 64;
      __hip_bfloat16* lb = ((wave < 2) ? As[ksub] : Bs[ksub]) + lboff;
#pragma unroll
      for (int c = 0; c < 8; ++c)
        async_copy16(gbase + (size_t)(c * 8 + sub) * DIM + k0 + gkoff, lb + c * 512);
    }
    __syncthreads();   // single drain for 16 deep-issued DMAs

    // compute this half: 4 ks steps, no barriers
#pragma unroll
    for (int ksub = 0; ksub < 2; ++ksub) {
      const __hip_bfloat16* Ab = As[ksub];
      const __hip_bfloat16* Bb = Bs[ksub];
#pragma unroll
      for (int ks = 0; ks < 2; ++ks) {
        const int phys = (ks * 4 + q) ^ lane7;  // physical 16B slot for this lane
        short8 a[4], b[4];
#pragma unroll
        for (int mt = 0; mt < 4; ++mt)
          a[mt] = *reinterpret_cast<const short8*>(
              Ab + (wm * 64 + mt * 16 + c16) * 64 + phys * 8);
#pragma unroll
        for (int nt = 0; nt < 4; ++nt)
          b[nt] = *reinterpret_cast<const short8*>(
              Bb + (wn * 64 + nt * 16 + c16) * 64 + phys * 8);
#pragma unroll
        for (int mt = 0; mt < 4; ++mt)
#pragma unroll
          for (int nt = 0; nt < 4; ++nt)
            acc[mt][nt] = __builtin_amdgcn_mfma_f32_16x16x32_bf16(
                a[mt], b[nt], acc[mt][nt], 0, 0, 0);
      }
    }
    if (h == 0) __syncthreads();   // all waves done reading before restage
  }

  __syncthreads();   // done with LDS tiles; rowsum/colsum init visible

  // ---- epilogue (verbatim r0/r7) ----
  // C/D layout: col = lane&15 (within nt-tile), row = q*4 + reg (within mt-tile).
  float colacc[4] = {0.f, 0.f, 0.f, 0.f};
  float pc = 0.f;
  const bool diagwave = (wm == wn);

#pragma unroll
  for (int mt = 0; mt < 4; ++mt) {
#pragma unroll
    for (int reg = 0; reg < 4; ++reg) {
      const bool onquad = (c16 == q * 4 + reg);  // lane holds a subtile-diag elem
      float s = 0.0f;
#pragma unroll
      for (int nt = 0; nt < 4; ++nt) {
        float e = __expf(2.0f * acc[mt][nt][reg] - 2.0f);
        bool skip = diagblk && diagwave && (nt == mt) && onquad;  // true self-sim
        s += skip ? 0.0f : e;
        colacc[nt] += e;
      }
      if (pairblk && diagwave && onquad) pc += acc[mt][mt][reg];  // pair dot
      s += __shfl_xor(s, 1, 64);
      s += __shfl_xor(s, 2, 64);
      s += __shfl_xor(s, 4, 64);
      s += __shfl_xor(s, 8, 64);
      if (c16 == 0)
        atomicAdd(&rowsum[wm * 64 + mt * 16 + q * 4 + reg], s);
    }
  }

  if (!diagblk) {
#pragma unroll
    for (int nt = 0; nt < 4; ++nt) {
      float cs = colacc[nt];
      cs += __shfl_xor(cs, 16, 64);
      cs += __shfl_xor(cs, 32, 64);
      if (lane < 16) atomicAdd(&colsum[wn * 64 + nt * 16 + lane], cs);
    }
  }

  if (pairblk && diagwave) {
#pragma unroll
    for (int m = 32; m >= 1; m >>= 1) pc += __shfl_xor(pc, m, 64);
    // each pair diag elem covers rows i and i+4096: loss += -2*(2*dot) per pair
    if (lane == 0) atomicAdd(out, -4.0f * pc * INV2N);
  }

  __syncthreads();
  if (tid < 128) {
    atomicAdd(&rowtotal[i0 + tid], rowsum[tid]);
    if (!diagblk) atomicAdd(&rowtotal[j0 + tid], colsum[tid]);
  }

  // ---- fence-free ticket finalize (verified r1/2/4/9/10) ----
  __syncthreads();
  if (tid == 0) lastflag = (atomicAdd(ticket, 1u) == (unsigned)(NTRI - 1)) ? 1 : 0;
  __syncthreads();
  if (lastflag) {
    __threadfence();      // acquire side; ONE block only (cheap)
    float v = 0.0f;
#pragma unroll 4
    for (int r = tid; r < TWO_N; r += 256) {
      float tv = __hip_atomic_load(&rowtotal[r], __ATOMIC_RELAXED,
                                   __HIP_MEMORY_SCOPE_AGENT);
      v += 2.0f + __logf(tv);
    }
#pragma unroll
    for (int m = 32; m >= 1; m >>= 1) v += __shfl_xor(v, m, 64);
    if (lane == 0) finsum[wave] = v;
    __syncthreads();
    if (tid == 0)
      atomicAdd(out, (finsum[0] + finsum[1] + finsum[2] + finsum[3]) * INV2N);
  }
}

// ---------------- launch ----------------
extern "C" void kernel_launch(void* const* d_in, const int* in_sizes, int n_in,
                              void* d_out, int out_size, void* d_ws, size_t ws_size,
                              hipStream_t stream) {
  const float* zi = (const float*)d_in[0];
  const float* zj = (const float*)d_in[1];
  float* out = (float*)d_out;

  __hip_bfloat16* zn = (__hip_bfloat16*)d_ws;                        // 8192*256*2 = 4 MB
  float* rowtotal = (float*)((char*)d_ws + (size_t)TWO_N * DIM * 2); // 8192*4 = 32 KB
  unsigned* ticket = (unsigned*)((char*)d_ws + (size_t)TWO_N * DIM * 2 + (size_t)TWO_N * 4);

  k_normalize<<<dim3(TWO_N / 4), dim3(256), 0, stream>>>(zi, zj, zn, rowtotal, out, ticket);
  k_simexp<<<dim3(NTRI), dim3(256), 0, stream>>>(zn, rowtotal, out, ticket);
}

// Round 12
// 90.162 us; speedup vs baseline: 1.7862x; 1.2459x over previous
//
#include <hip/hip_runtime.h>
#include <hip/hip_bf16.h>
#include <math.h>

// NT-Xent loss, N=4096, D=256, symmetric-GEMM version.
// loss = (1/2N) * sum_i [ 2 + log( sum_{j != i} exp(2*dot_ij - 2) ) - 2*dot(zn_i, zn_pair(i)) ]
//
// ROUND-12: K-loop = r0 verbatim (best across 12 rounds; every K-loop axis
// ablated to null/worse). NEW: the epilogue -- identical in all prior rounds,
// never ablated -- loses its 64 serial shfl_xor chains + 16 LDS atomics per
// lane. Row partials go to a padded LDS scratch [128][33] f32 (overlaid on
// As/Bs, dead after the K-loop; pad 33 => conflict-free reads), one barrier,
// then 128 threads each sum 32 values and issue ONE global atomicAdd.
// Plus XCD-bijective swizzle (2080 = 8*260; r10/r11: FETCH -27%).
// K1: normalize rows -> bf16 zn; zero rowtotal[8192] and out.
// K2: 2080 upper-tri 128x128 tiles, 4 waves 2x2, r0 staging/swizzle/MFMA.
// K3: 32 blocks: loss += sum_i (2 + log(rowtotal[i])) / 2N.

using short8  = __attribute__((ext_vector_type(8))) short;
using floatx4 = __attribute__((ext_vector_type(4))) float;

constexpr int TWO_N = 8192;
constexpr int DIM   = 256;
constexpr int NB    = 64;                 // 8192/128 tile blocks per side
constexpr int NTRI  = NB * (NB + 1) / 2;  // 2080
constexpr float INV2N = 1.0f / 8192.0f;

__device__ static inline unsigned short f2bf(float f) {
  unsigned u = __float_as_uint(f);
  return (unsigned short)((u + 0x7fffu + ((u >> 16) & 1u)) >> 16);  // RNE
}

__device__ static inline void async_copy16(const __hip_bfloat16* g, __hip_bfloat16* l) {
  __builtin_amdgcn_global_load_lds(
      (const __attribute__((address_space(1))) void*)(const void*)g,
      (__attribute__((address_space(3))) void*)(void*)l, 16, 0, 0);
}

// ---------------- K1: normalize + cast to bf16, zero accumulators ----------------
__global__ __launch_bounds__(256) void k_normalize(
    const float* __restrict__ zi, const float* __restrict__ zj,
    __hip_bfloat16* __restrict__ zn, float* __restrict__ rowtotal,
    float* __restrict__ out)
{
  if (blockIdx.x == 0 && threadIdx.x == 0) out[0] = 0.0f;
  if (blockIdx.x < 32) rowtotal[blockIdx.x * 256 + threadIdx.x] = 0.0f;

  const int lane = threadIdx.x & 63;
  const int wave = threadIdx.x >> 6;
  const int row  = blockIdx.x * 4 + wave;
  const float* src = (row < 4096) ? (zi + (size_t)row * DIM)
                                  : (zj + (size_t)(row - 4096) * DIM);
  float4 v = reinterpret_cast<const float4*>(src)[lane];
  float ss = v.x * v.x + v.y * v.y + v.z * v.z + v.w * v.w;
#pragma unroll
  for (int m = 32; m >= 1; m >>= 1) ss += __shfl_xor(ss, m, 64);
  float inv = 1.0f / fmaxf(sqrtf(ss), 1e-8f);
  ushort4 o;
  o.x = f2bf(v.x * inv); o.y = f2bf(v.y * inv);
  o.z = f2bf(v.z * inv); o.w = f2bf(v.w * inv);
  reinterpret_cast<ushort4*>(zn + (size_t)row * DIM)[lane] = o;
}

// ---------------- K2: triangular GEMM (r0) + parallel-scratch epilogue ----------------
// block 256 = 4 waves in 2x2; wave owns 64x64 (4x4 of 16x16x32 accumulators).
// LDS tiles [128][64] bf16 with 16B-slot XOR swizzle: phys_slot = logical ^ (row&7).
__global__ __launch_bounds__(256) void k_simexp(
    const __hip_bfloat16* __restrict__ Z, float* __restrict__ rowtotal,
    float* __restrict__ out)
{
  // 32 KB shared pool: As|Bs during the K-loop, scratch[128][33] f32 after.
  __shared__ __align__(16) char smem[128 * 64 * 2 * 2];
  __shared__ float colsum[128];
  __hip_bfloat16* As = (__hip_bfloat16*)smem;
  __hip_bfloat16* Bs = As + 128 * 64;
  float* scratch = (float*)smem;            // 128*33*4 = 16.9 KB <= 32 KB

  const int tid  = threadIdx.x;
  const int lane = tid & 63;
  const int wave = tid >> 6;
  const int wm   = wave >> 1;   // output row half
  const int wn   = wave & 1;    // output col half

  // XCD-bijective chunked swizzle: 2080 = 8 * 260 (T1; r10/r11 FETCH -27%)
  const int bid = blockIdx.x;
  const int u   = (bid & 7) * (NTRI / 8) + (bid >> 3);

  // triangular decode: u -> (ib <= jb)
  int jb = (int)((sqrtf(8.0f * (float)u + 1.0f) - 1.0f) * 0.5f);
  while ((jb + 1) * (jb + 2) / 2 <= u) ++jb;
  while (jb * (jb + 1) / 2 > u) --jb;
  const int ib = u - jb * (jb + 1) / 2;

  const bool diagblk = (ib == jb);
  const bool pairblk = (jb == ib + 32);
  const int i0 = ib * 128;
  const int j0 = jb * 128;

  if (tid < 128) colsum[tid] = 0.0f;

  floatx4 acc[4][4] = {};

  const int lane7 = lane & 7;
  const int sub   = lane >> 3;               // 0..7 subrow within 8-row segment
  const int gkoff = ((lane7 ^ sub) << 3);    // swizzled logical 16B slot to fetch
  const int q     = lane >> 4;               // 0..3
  const int c16   = lane & 15;

  // staging bases: waves 0,1 -> As (rows 0..63 / 64..127), waves 2,3 -> Bs
  const __hip_bfloat16* gbase =
      Z + (size_t)((wave < 2 ? i0 : j0) + (wave & 1) * 64) * DIM;
  __hip_bfloat16* lbase = ((wave < 2) ? As : Bs) + (wave & 1) * 64 * 64;

  for (int kk = 0; kk < 4; ++kk) {
    const int k0 = kk * 64;
#pragma unroll
    for (int c = 0; c < 8; ++c) {
      const __hip_bfloat16* gp = gbase + (size_t)(c * 8 + sub) * DIM + k0 + gkoff;
      async_copy16(gp, lbase + c * 512);   // + lane*16B implicit
    }
    __syncthreads();

#pragma unroll
    for (int ks = 0; ks < 2; ++ks) {
      const int phys = (ks * 4 + q) ^ lane7;  // physical 16B slot for this lane
      short8 a[4], b[4];
#pragma unroll
      for (int mt = 0; mt < 4; ++mt)
        a[mt] = *reinterpret_cast<const short8*>(
            As + (wm * 64 + mt * 16 + c16) * 64 + phys * 8);
#pragma unroll
      for (int nt = 0; nt < 4; ++nt)
        b[nt] = *reinterpret_cast<const short8*>(
            Bs + (wn * 64 + nt * 16 + c16) * 64 + phys * 8);
#pragma unroll
      for (int mt = 0; mt < 4; ++mt)
#pragma unroll
        for (int nt = 0; nt < 4; ++nt)
          acc[mt][nt] = __builtin_amdgcn_mfma_f32_16x16x32_bf16(
              a[mt], b[nt], acc[mt][nt], 0, 0, 0);
    }
    __syncthreads();
  }

  // ---- epilogue (parallel-scratch) ----
  // C/D layout: col = lane&15 (within nt-tile), row = q*4 + reg (within mt-tile).
  float colacc[4] = {0.f, 0.f, 0.f, 0.f};
  float rowacc[4][4];
  float pc = 0.f;
  const bool diagwave = (wm == wn);

#pragma unroll
  for (int mt = 0; mt < 4; ++mt) {
#pragma unroll
    for (int reg = 0; reg < 4; ++reg) {
      const bool onquad = (c16 == q * 4 + reg);  // lane holds a subtile-diag elem
      float s = 0.0f;
#pragma unroll
      for (int nt = 0; nt < 4; ++nt) {
        float e = __expf(2.0f * acc[mt][nt][reg] - 2.0f);
        bool skip = diagblk && diagwave && (nt == mt) && onquad;  // true self-sim
        s += skip ? 0.0f : e;
        colacc[nt] += e;    // diag contamination discarded (no colsum flush there)
      }
      if (pairblk && diagwave && onquad) pc += acc[mt][mt][reg];  // pair dot
      rowacc[mt][reg] = s;
    }
  }

  // column sums: reduce over the 4 q-groups (2 shfls), flush by lanes 0..15
  if (!diagblk) {
#pragma unroll
    for (int nt = 0; nt < 4; ++nt) {
      float cs = colacc[nt];
      cs += __shfl_xor(cs, 16, 64);
      cs += __shfl_xor(cs, 32, 64);
      if (lane < 16) atomicAdd(&colsum[wn * 64 + nt * 16 + lane], cs);
    }
  }

  if (pairblk && diagwave) {
#pragma unroll
    for (int m = 32; m >= 1; m >>= 1) pc += __shfl_xor(pc, m, 64);
    // each pair diag elem covers rows i and i+4096: loss += -2*(2*dot) per pair
    if (lane == 0) atomicAdd(out, -4.0f * pc * INV2N);
  }

  // row partials -> scratch[row][wn*16 + c16]  (pad 33 => conflict-free reads)
#pragma unroll
  for (int mt = 0; mt < 4; ++mt)
#pragma unroll
    for (int reg = 0; reg < 4; ++reg)
      scratch[(wm * 64 + mt * 16 + q * 4 + reg) * 33 + wn * 16 + c16] =
          rowacc[mt][reg];

  __syncthreads();   // scratch writes + colsum atomics complete

  if (tid < 128) {
    float rs = 0.0f;
#pragma unroll
    for (int k = 0; k < 32; ++k) rs += scratch[tid * 33 + k];
    atomicAdd(&rowtotal[i0 + tid], rs);
    if (!diagblk) atomicAdd(&rowtotal[j0 + tid], colsum[tid]);
  }
}

// ---------------- K3: finalize (logs + reduce) ----------------
__global__ __launch_bounds__(256) void k_finalize(
    const float* __restrict__ rowtotal, float* __restrict__ out)
{
  __shared__ float wsum[4];
  const int lane = threadIdx.x & 63;
  const int wave = threadIdx.x >> 6;
  const int row  = blockIdx.x * 256 + threadIdx.x;
  float v = 2.0f + __logf(rowtotal[row]);
#pragma unroll
  for (int m = 32; m >= 1; m >>= 1) v += __shfl_xor(v, m, 64);
  if (lane == 0) wsum[wave] = v;
  __syncthreads();
  if (threadIdx.x == 0)
    atomicAdd(out, (wsum[0] + wsum[1] + wsum[2] + wsum[3]) * INV2N);
}

// ---------------- launch ----------------
extern "C" void kernel_launch(void* const* d_in, const int* in_sizes, int n_in,
                              void* d_out, int out_size, void* d_ws, size_t ws_size,
                              hipStream_t stream) {
  const float* zi = (const float*)d_in[0];
  const float* zj = (const float*)d_in[1];
  float* out = (float*)d_out;

  __hip_bfloat16* zn = (__hip_bfloat16*)d_ws;                        // 8192*256*2 = 4 MB
  float* rowtotal = (float*)((char*)d_ws + (size_t)TWO_N * DIM * 2); // 8192*4 = 32 KB

  k_normalize<<<dim3(TWO_N / 4), dim3(256), 0, stream>>>(zi, zj, zn, rowtotal, out);
  k_simexp<<<dim3(NTRI), dim3(256), 0, stream>>>(zn, rowtotal, out);
  k_finalize<<<dim3(TWO_N / 256), dim3(256), 0, stream>>>(rowtotal, out);
}